// Round 17
// baseline (306.384 us; speedup 1.0000x reference)
//
#include <hip/hip_runtime.h>
#include <math.h>
#include <float.h>

#ifndef M_PI
#define M_PI 3.14159265358979323846
#endif

#define N_FFT       512
#define N_BINS      257
#define N_FILTERS   128
#define OUTPUT_SIZE 262144
#define N_TIMESTEPS 128

typedef int int4v __attribute__((ext_vector_type(4)));
typedef float f32x4 __attribute__((ext_vector_type(4)));

// ---- ordered-uint64 encoding for deterministic double atomic min/max ----
__device__ __forceinline__ unsigned long long enc_d(double f) {
    unsigned long long u = (unsigned long long)__double_as_longlong(f);
    return (u & 0x8000000000000000ull) ? ~u : (u | 0x8000000000000000ull);
}
__device__ __forceinline__ double dec_d(unsigned long long e) {
    unsigned long long u = (e & 0x8000000000000000ull) ? (e ^ 0x8000000000000000ull) : ~e;
    return __longlong_as_double((long long)u);
}

// ============================================================================
// K1a: DFT, one block per bin (257 blocks x 64 threads) — verified round 7.
// ============================================================================
__global__ __launch_bounds__(64) void k1a_dft(
    const float* __restrict__ audio, float* __restrict__ mag,
    unsigned long long* __restrict__ minmax)
{
    __shared__ double sre[64];
    __shared__ double sim[64];

    const int b    = blockIdx.x;     // bin 0..256
    const int lane = threadIdx.x;    // 0..63

    double re = 0.0, im = 0.0;
    #pragma unroll
    for (int j = 0; j < 8; ++j) {
        const int n = lane * 8 + j;              // rfft(n=512): first 512 samples
        const int m = (b * n) & (N_FFT - 1);
        double s, c;
        sincos((-2.0 * M_PI * (double)m) / (double)N_FFT, &s, &c);
        const double a = (double)audio[n];
        re += a * c;
        im += a * s;
    }
    sre[lane] = re;
    sim[lane] = im;
    __syncthreads();
    #pragma unroll
    for (int s = 32; s > 0; s >>= 1) {
        if (lane < s) {
            sre[lane] += sre[lane + s];
            sim[lane] += sim[lane + s];
        }
        __syncthreads();
    }
    if (lane == 0) {
        mag[b] = (float)sqrt(sre[0] * sre[0] + sim[0] * sim[0]);
        if (b == 0) {
            minmax[0] = 0xFFFFFFFFFFFFFFFFull;  // min slot
            minmax[1] = 0ull;                   // max slot
        }
    }
}

// ============================================================================
// K2: ROUND 17 "reg-staged LDS GEMV" — same theory as the R13 design
//   (coalesced HBM staging + shfl-free lane-owns-row fp64 compute from LDS),
//   but WITHOUT __builtin_amdgcn_global_load_lds: after 5 infra-failed
//   submissions I can't rule out a hipcc hang on that construct, so this
//   variant uses the known-good plain-HIP staging path (global f32x4 load ->
//   ds_write at swizzled address).
//   Evidence triangle driving the design:
//     R6  lane-owns-row direct: bit-exact, shfl-free, uncoalesced -> 74us.
//     R9  split-K:              FETCH 179MB line-thrash -> 83us.
//     R11 waverow:              coalesced (67MB) but 5-deep fp64 shfl chain
//                               per row -> 86us, VALUBusy 7%.
//   Staging: 32 iters x 128 threads, gsrc[i*128+tid] — consecutive threads
//   read consecutive f32x4 -> fully coalesced 2KB/instruction; iterations
//   independent -> natural pipelining (R10-proven mechanism). LDS write at
//   byte = row*512 + ((slot<<4) ^ ((row&31)<<4)): 32 lanes/row span all 32
//   banks (4 accesses/bank = ds_write_b128 floor). Read back with the same
//   XOR (bijective per row; read row == tid) -> conflict-free.
//   Compute: k-ascending fp64, comp 0..3 — BIT-IDENTICAL accumulation to
//   the verified baseline, zero cross-lane ops.
// ============================================================================
__global__ __launch_bounds__(128) void k2_gemv(
    const f32x4* __restrict__ W4, const float* __restrict__ bias,
    const float* __restrict__ fb, const float* __restrict__ mag,
    const float* __restrict__ adapt, double* __restrict__ activity,
    unsigned long long* __restrict__ minmax)
{
    __shared__ float  tile[128 * 128];   // 64 KB, rows swizzled
    __shared__ float  magl[N_BINS];
    __shared__ double ad[N_FILTERS];
    __shared__ double red_min[128];
    __shared__ double red_max[128];

    const int tid = threadIdx.x;         // 0..127

    for (int j = tid; j < N_BINS; j += 128) magl[j] = mag[j];

    // ---- stage W-tile: coalesced loads -> swizzled ds_write ----
    const f32x4* gsrc = W4 + (size_t)blockIdx.x * 4096;   // 128 rows x 32 slots
    #pragma unroll
    for (int i = 0; i < 32; i += 4) {
        const f32x4 v0 = gsrc[(i + 0) * 128 + tid];
        const f32x4 v1 = gsrc[(i + 1) * 128 + tid];
        const f32x4 v2 = gsrc[(i + 2) * 128 + tid];
        const f32x4 v3 = gsrc[(i + 3) * 128 + tid];
        const int i0 = (i + 0) * 128 + tid;
        const int i1 = (i + 1) * 128 + tid;
        const int i2 = (i + 2) * 128 + tid;
        const int i3 = (i + 3) * 128 + tid;
        // idx -> row = idx>>5, slot = idx&31; swizzled byte offset
        *(f32x4*)((char*)tile + (i0 >> 5) * 512 +
                  (((i0 & 31) << 4) ^ (((i0 >> 5) & 31) << 4))) = v0;
        *(f32x4*)((char*)tile + (i1 >> 5) * 512 +
                  (((i1 & 31) << 4) ^ (((i1 >> 5) & 31) << 4))) = v1;
        *(f32x4*)((char*)tile + (i2 >> 5) * 512 +
                  (((i2 & 31) << 4) ^ (((i2 >> 5) & 31) << 4))) = v2;
        *(f32x4*)((char*)tile + (i3 >> 5) * 512 +
                  (((i3 & 31) << 4) ^ (((i3 >> 5) & 31) << 4))) = v3;
    }

    // ---- front-end: ad[tid] for all 128 threads (overlaps staging drain) ----
    {
        const float* row = fb + tid * N_BINS;
        double acc = 0.0;
        int j = 0;
        #pragma unroll 1
        for (int b = 0; b < 8; ++b) {          // 8 x 32 = 256 bins
            float r[32];
            #pragma unroll
            for (int u = 0; u < 32; ++u) r[u] = row[j + u];
            #pragma unroll
            for (int u = 0; u < 32; ++u)
                acc += (double)r[u] * (double)magl[j + u];
            j += 32;
        }
        acc += (double)row[256] * (double)magl[256];   // remainder bin
        const double x = acc + 1e-6;               // + LATENCY_EPSILON
        const double p = pow(x, 0.3);
        const double a = p - (double)adapt[tid] * 0.5;
        ad[tid] = a > 0.0 ? a : 0.0;               // relu
    }
    __syncthreads();   // tile + ad visible

    // ---- GEMV: one row per thread, from swizzled LDS tile ----
    const int swz = (tid & 31) << 4;
    const char* rbase = (const char*)tile + tid * 512;
    double acc = 0.0;
    #pragma unroll 8
    for (int k4 = 0; k4 < 32; ++k4) {
        const f32x4 w = *(const f32x4*)(rbase + ((k4 * 16) ^ swz));
        const int k = k4 * 4;
        acc += (double)w[0] * ad[k];
        acc += (double)w[1] * ad[k + 1];
        acc += (double)w[2] * ad[k + 2];
        acc += (double)w[3] * ad[k + 3];
    }
    const int r = blockIdx.x * 128 + tid;
    const double a = acc + (double)bias[r];
    activity[r] = a;

    red_min[tid] = a;
    red_max[tid] = a;
    __syncthreads();
    for (int s = 64; s > 0; s >>= 1) {
        if (tid < s) {
            red_min[tid] = fmin(red_min[tid], red_min[tid + s]);
            red_max[tid] = fmax(red_max[tid], red_max[tid + s]);
        }
        __syncthreads();
    }
    if (tid == 0) {
        atomicMin(&minmax[0], enc_d(red_min[0]));
        atomicMax(&minmax[1], enc_d(red_max[0]));
    }
}

// ============================================================================
// K3: latency coding + spike-matrix write (int32 out), fp64 quantization.
//   At the copy ceiling already (512 MiB @ ~6.7 TB/s ~= 80 us) — leave as is.
// ============================================================================
__global__ __launch_bounds__(256) void k3_spikes(
    const double* __restrict__ activity,
    const unsigned long long* __restrict__ minmax,
    int4v* __restrict__ out4)
{
    const int tid = blockIdx.x * 256 + threadIdx.x;  // 0..65535
    const double amin = dec_d(minmax[0]);
    const double amax = dec_d(minmax[1]);
    const double denom = (amax - amin) + 1e-6;

    const double nx = (activity[4 * tid + 0] - amin) / denom;
    const double ny = (activity[4 * tid + 1] - amin) / denom;
    const double nz = (activity[4 * tid + 2] - amin) / denom;
    const double nw = (activity[4 * tid + 3] - amin) / denom;

    const int lx = (int)((1.0 - nx) * 127.0);
    const int ly = (int)((1.0 - ny) * 127.0);
    const int lz = (int)((1.0 - nz) * 127.0);
    const int lw = (int)((1.0 - nw) * 127.0);

    const int vx = (nx > 0.05) ? 1 : 0;
    const int vy = (ny > 0.05) ? 1 : 0;
    const int vz = (nz > 0.05) ? 1 : 0;
    const int vw = (nw > 0.05) ? 1 : 0;

    const int t0 = blockIdx.y * (N_TIMESTEPS / 4);
    #pragma unroll 8
    for (int t = t0; t < t0 + N_TIMESTEPS / 4; ++t) {
        int4v v;
        v.x = (lx == t) ? vx : 0;
        v.y = (ly == t) ? vy : 0;
        v.z = (lz == t) ? vz : 0;
        v.w = (lw == t) ? vw : 0;
        out4[(size_t)t * (OUTPUT_SIZE / 4) + tid] = v;
    }
}

// ============================================================================
extern "C" void kernel_launch(void* const* d_in, const int* in_sizes, int n_in,
                              void* d_out, int out_size, void* d_ws, size_t ws_size,
                              hipStream_t stream) {
    (void)in_sizes; (void)n_in; (void)out_size; (void)ws_size;

    const float* audio = (const float*)d_in[0];   // [16000]
    const float* fb    = (const float*)d_in[1];   // [128, 257]
    const float* W     = (const float*)d_in[2];   // [262144, 128]
    const float* bias  = (const float*)d_in[3];   // [262144]
    const float* adapt = (const float*)d_in[4];   // [128]
    int* out = (int*)d_out;                       // [128, 262144] bool -> int32

    double* activity = (double*)d_ws;                              // 262144 f64
    unsigned long long* minmax =
        (unsigned long long*)(activity + OUTPUT_SIZE);             // 2 u64
    float* mag = (float*)(minmax + 2);                             // 257 f32

    k1a_dft<<<N_BINS, 64, 0, stream>>>(audio, mag, minmax);
    k2_gemv<<<OUTPUT_SIZE / 128, 128, 0, stream>>>(
        (const f32x4*)W, bias, fb, mag, adapt, activity, minmax);
    k3_spikes<<<dim3(OUTPUT_SIZE / 4 / 256, 4), 256, 0, stream>>>(
        activity, minmax, (int4v*)out);
}